// Round 7
// baseline (430.505 us; speedup 1.0000x reference)
//
#include <hip/hip_runtime.h>
#include <math.h>

#define NN_K 32
#define E_DIM 512
#define CLAMP_V 10000.0f
#define NBLK 768            // 3 blocks/CU x 256 CUs: co-resident by construction

typedef __attribute__((ext_vector_type(8))) short short8;
typedef __attribute__((ext_vector_type(4))) float f32x4;

// bf16 RTNE, bit-level
__device__ __forceinline__ unsigned short f2bf(float x) {
  unsigned u = __float_as_uint(x);
  unsigned r = u + 0x7fffu + ((u >> 16) & 1u);
  return (unsigned short)(r >> 16);
}
__device__ __forceinline__ float bf2f_bits(short h) {
  return __uint_as_float(((unsigned)(unsigned short)h) << 16);
}
__device__ __forceinline__ void async16(const void* g, void* l) {
  __builtin_amdgcn_global_load_lds((const __attribute__((address_space(1))) void*)g,
                                   (__attribute__((address_space(3))) void*)l, 16, 0, 0);
}

// device-scope grid barrier: arrive (atomic inc) + spin until all NBLK arrived.
// counters zeroed by a hipMemsetAsync node before the kernel each iteration.
// threadfence = agent-scope release/acquire (cross-XCD L2 wb/inv on gfx950).
__device__ __forceinline__ void grid_barrier(unsigned* cnt) {
  __syncthreads();
  if (threadIdx.x == 0) {
    __threadfence();
    atomicAdd(cnt, 1u);
    while (atomicAdd(cnt, 0u) < NBLK) __builtin_amdgcn_s_sleep(2);
    __threadfence();
  }
  __syncthreads();
}

// ---------------------------------------------------------------------------
// 64x64-tile bf16 MFMA GEMM step (BK=32, 16 iters, dbuf vmcnt(2) pipeline).
// 4 waves, each computing a 32x32 quadrant (2x2 16x16x32 MFMAs / iter).
// ---------------------------------------------------------------------------
__device__ __forceinline__ void gemm64(
    const short* __restrict__ A, const short* __restrict__ W,
    const float* __restrict__ bias,
    float* __restrict__ outf, short* __restrict__ outb,
    int out_ld, int out_c0, int Mstore, int row0, int col0, bool doClamp,
    short (*sA)[2048], short (*sB)[2048])
{
  int t = threadIdx.x;
  int cr = t >> 2, ck = (t & 3) << 3;
  const short* gA = A + (size_t)(row0 + cr) * 512 + ck;
  const short* gB = W + (size_t)(col0 + cr) * 512 + ck;
  int lo = t * 8;
  int lane = t & 63, w = t >> 6;
  int wm = (w & 1) << 5, wn = (w >> 1) << 5;
  int lr = lane & 15, lq = lane >> 4;

#define STG(tt, b) { async16(gA + (tt) * 32, &sA[b][lo]); \
                     async16(gB + (tt) * 32, &sB[b][lo]); }
  STG(0, 0);
  STG(1, 1);

  f32x4 acc[2][2];
  #pragma unroll
  for (int i = 0; i < 2; ++i)
    #pragma unroll
    for (int j = 0; j < 2; ++j)
      acc[i][j] = (f32x4){0.f, 0.f, 0.f, 0.f};

  #pragma unroll
  for (int it = 0; it < 16; ++it) {
    int cur = it & 1;
    if (it == 15) asm volatile("s_waitcnt vmcnt(0)\ns_barrier" ::: "memory");
    else          asm volatile("s_waitcnt vmcnt(2)\ns_barrier" ::: "memory");

    short8 af[2], bfr[2];
    #pragma unroll
    for (int i = 0; i < 2; ++i) {
      af[i]  = *(const short8*)&sA[cur][(wm + (i << 4) + lr) * 32 + (lq << 3)];
      bfr[i] = *(const short8*)&sB[cur][(wn + (i << 4) + lr) * 32 + (lq << 3)];
    }
    #pragma unroll
    for (int i = 0; i < 2; ++i)
      #pragma unroll
      for (int j = 0; j < 2; ++j)
        acc[i][j] = __builtin_amdgcn_mfma_f32_16x16x32_bf16(af[i], bfr[j], acc[i][j], 0, 0, 0);

    asm volatile("s_waitcnt lgkmcnt(0)\ns_barrier" ::: "memory");
    if (it + 2 < 16) STG(it + 2, cur);
  }
#undef STG

  #pragma unroll
  for (int j = 0; j < 2; ++j) {
    int gcol = col0 + wn + (j << 4) + lr;
    float bv_ = bias[gcol];
    #pragma unroll
    for (int i = 0; i < 2; ++i) {
      #pragma unroll
      for (int rr = 0; rr < 4; ++rr) {
        int grow = row0 + wm + (i << 4) + (lq << 2) + rr;
        if (grow < Mstore) {
          float v = acc[i][j][rr] + bv_;
          if (doClamp) {
            v = isnan(v) ? 0.0f : v;
            v = fminf(fmaxf(v, -CLAMP_V), CLAMP_V);
          }
          if (outf) outf[(size_t)grow * 512 + gcol] = v;
          else      outb[(size_t)grow * out_ld + out_c0 + gcol] = (short)f2bf(v);
        }
      }
    }
  }
}

// ---------------------------------------------------------------------------
// Mega-kernel: A(front) -> B(qkv) -> C(attn) -> D(out) with grid barriers.
// ---------------------------------------------------------------------------
__global__ __launch_bounds__(256, 3) void mega_kernel(
    const float* __restrict__ x, const float* __restrict__ coords9,
    const float* __restrict__ prompt,
    const float* __restrict__ w1, const float* __restrict__ b1,
    const float* __restrict__ ln_g, const float* __restrict__ ln_b,
    const float* __restrict__ wq, const float* __restrict__ wk,
    const float* __restrict__ wv, const float* __restrict__ wo,
    const float* __restrict__ bq, const float* __restrict__ bk,
    const float* __restrict__ bv, const float* __restrict__ bo,
    short* __restrict__ w_bf, short* __restrict__ pos_bf,
    int* __restrict__ topkb, float* __restrict__ qb, short* __restrict__ kv,
    short* __restrict__ ctx_bf, float* __restrict__ outp,
    unsigned* __restrict__ bar, int N, int Mpad)
{
  __shared__ union {
    struct { float red[8]; } pos;
    struct { unsigned hist[256]; unsigned waveSums[4];
             unsigned sel_bin, sel_rem, cnt, tcnt; unsigned tie[2048]; } tk;
    struct { short sA[2][2048]; short sB[2][2048]; } gm;           // 16 KB
    struct { short klds[16384]; int sidx[NN_K]; float plds[256]; } at; // 33.9 KB
  } S;

  int blk = blockIdx.x, t = threadIdx.x;
  int lane = t & 63, wv_ = t >> 6;

  //========================= Phase A: front =========================
  // wconv: 262144 float4s, grid-stride
  #pragma unroll
  for (int i = 0; i < 2; ++i) {
    int v = blk * 256 + t + i * (NBLK * 256);
    if (v < 262144) {
      int m = v >> 16, e = v & 0xffff;
      const float* src = m == 0 ? wq : (m == 1 ? wk : (m == 2 ? wv : wo));
      float4 f = ((const float4*)src)[e];
      short4 h;
      h.x = (short)f2bf(f.x); h.y = (short)f2bf(f.y);
      h.z = (short)f2bf(f.z); h.w = (short)f2bf(f.w);
      ((short4*)w_bf)[v] = h;
    }
  }
  // pos: up to 3 rows per block
  for (int r = 0; r < 3; ++r) {
    int n = blk + r * NBLK;
    if (n >= Mpad) break;
    size_t rb = (size_t)n * E_DIM;
    if (n >= N) {
      for (int j = t; j < E_DIM; j += 256) pos_bf[rb + j] = 0;
      continue;
    }
    __syncthreads();
    float g = 0.f, d = 0.f;
    if (t < 128) {
      const float* c9 = coords9 + n * 9;
      float c0 = (c9[0] + c9[3] + c9[6]) / 3.0f;
      float c1 = (c9[1] + c9[4] + c9[7]) / 3.0f;
      float c2 = (c9[2] + c9[5] + c9[8]) / 3.0f;
      float pre = c0 * w1[t*3+0] + c1 * w1[t*3+1] + c2 * w1[t*3+2] + b1[t];
      g = 0.5f * pre * (1.0f + erff(pre * 0.70710678118654752440f));
      float s = g;
      #pragma unroll
      for (int o = 32; o > 0; o >>= 1) s += __shfl_xor(s, o);
      if ((t & 63) == 0) S.pos.red[t >> 6] = s;
    }
    __syncthreads();
    if (t < 128) {
      float mu = (S.pos.red[0] + S.pos.red[1]) * (1.0f / 128.0f);
      d = g - mu;
      float s2 = d * d;
      #pragma unroll
      for (int o = 32; o > 0; o >>= 1) s2 += __shfl_xor(s2, o);
      if ((t & 63) == 0) S.pos.red[2 + (t >> 6)] = s2;
    }
    __syncthreads();
    if (t < 128) {
      float var = (S.pos.red[2] + S.pos.red[3]) * (1.0f / 128.0f);
      float y = d * rsqrtf(var + 1e-5f) * ln_g[t] + ln_b[t];
      pos_bf[rb + 384 + t] = (short)f2bf(y);
    }
    for (int j = t; j < 384; j += 256)
      pos_bf[rb + j] = (short)f2bf(x[rb + j] + prompt[j]);
  }
  // topk: up to 3 rows per block, centroids computed inline (bit-identical)
  for (int r = 0; r < 3; ++r) {
    int n = blk + r * NBLK;
    if (n >= N) break;
    __syncthreads();
    const float* cn = coords9 + n * 9;
    float cx = (cn[0] + cn[3] + cn[6]) / 3.0f;
    float cy = (cn[1] + cn[4] + cn[7]) / 3.0f;
    float cz = (cn[2] + cn[5] + cn[8]) / 3.0f;
    unsigned bits[8];
    #pragma unroll
    for (int rr = 0; rr < 8; ++rr) {
      int m = t + (rr << 8);
      unsigned b = 0xFFFFFFFFu;
      if (m < N) {
        const float* cm = coords9 + m * 9;
        float mx_ = (cm[0] + cm[3] + cm[6]) / 3.0f;
        float my_ = (cm[1] + cm[4] + cm[7]) / 3.0f;
        float mz_ = (cm[2] + cm[5] + cm[8]) / 3.0f;
        float dx = cx - mx_, dy = cy - my_, dz = cz - mz_;
        b = __float_as_uint(sqrtf(dx*dx + dy*dy + dz*dz));
      }
      bits[rr] = b;
    }
    unsigned prefix = 0, K_rem = NN_K;
    #pragma unroll
    for (int p = 0; p < 4; ++p) {
      int shift = 24 - 8 * p;
      unsigned high_mask = (p == 0) ? 0u : (0xFFFFFFFFu << (8 * (4 - p)));
      S.tk.hist[t] = 0;
      __syncthreads();
      #pragma unroll
      for (int rr = 0; rr < 8; ++rr)
        if ((bits[rr] & high_mask) == prefix)
          atomicAdd(&S.tk.hist[(bits[rr] >> shift) & 255], 1u);
      __syncthreads();
      unsigned h = S.tk.hist[t];
      unsigned scan = h;
      #pragma unroll
      for (int o = 1; o < 64; o <<= 1) {
        unsigned u = __shfl_up(scan, o);
        if (lane >= o) scan += u;
      }
      if (lane == 63) S.tk.waveSums[wv_] = scan;
      __syncthreads();
      unsigned off = 0;
      for (int w2 = 0; w2 < wv_; ++w2) off += S.tk.waveSums[w2];
      scan += off;
      if (scan >= K_rem && (scan - h) < K_rem) {
        S.tk.sel_bin = (unsigned)t;
        S.tk.sel_rem = K_rem - (scan - h);
      }
      __syncthreads();
      prefix |= S.tk.sel_bin << shift;
      K_rem = S.tk.sel_rem;
      __syncthreads();
    }
    unsigned T = prefix;
    if (t == 0) { S.tk.cnt = 0; S.tk.tcnt = 0; }
    __syncthreads();
    #pragma unroll
    for (int rr = 0; rr < 8; ++rr) {
      int m = t + (rr << 8);
      if (m < N) {
        if (bits[rr] < T) {
          unsigned slot = atomicAdd(&S.tk.cnt, 1u);
          topkb[n * NN_K + slot] = m;
        } else if (bits[rr] == T) {
          unsigned tp = atomicAdd(&S.tk.tcnt, 1u);
          S.tk.tie[tp] = (unsigned)m;
        }
      }
    }
    __syncthreads();
    if (t == 0) {
      unsigned base = S.tk.cnt, need = K_rem;
      for (unsigned it = 0; it < need; ++it) {
        unsigned best = 0xFFFFFFFFu, bj = 0;
        for (unsigned j = 0; j < S.tk.tcnt; ++j)
          if (S.tk.tie[j] < best) { best = S.tk.tie[j]; bj = j; }
        topkb[n * NN_K + base + it] = (int)best;
        S.tk.tie[bj] = 0xFFFFFFFFu;
      }
    }
  }

  //========================= Phase B: qkv =========================
  grid_barrier(&bar[0]);
  {
    int sel = blk / 256, rem = blk & 255;          // 768 = 3 x (32x8) tiles
    int r0 = (rem >> 3) << 6, c0 = (rem & 7) << 6;
    const short* W = w_bf + (size_t)sel * 262144;
    if (sel == 0)
      gemm64(pos_bf, W, bq, qb, nullptr, 512, 0, Mpad, r0, c0, false, S.gm.sA, S.gm.sB);
    else if (sel == 1)
      gemm64(pos_bf, W, bk, nullptr, kv, 1024, 0, Mpad, r0, c0, false, S.gm.sA, S.gm.sB);
    else
      gemm64(pos_bf, W, bv, nullptr, kv, 1024, 512, Mpad, r0, c0, false, S.gm.sA, S.gm.sB);
  }

  //========================= Phase C: attn =========================
  grid_barrier(&bar[1]);
  for (int r = 0; r < 3; ++r) {
    int n = blk + r * NBLK;
    if (n >= Mpad) break;
    size_t rb = (size_t)n * E_DIM;
    __syncthreads();                                // klds reuse across r
    if (n >= N) {
      for (int j = t; j < E_DIM; j += 256) ctx_bf[rb + j] = 0;
      continue;
    }
    if (t < NN_K) S.at.sidx[t] = topkb[n * NN_K + t];
    {
      int j = t >> 3, a = t & 7;                    // 8 threads per k-row
      int row = topkb[n * NN_K + j];
      const short8* src = (const short8*)(kv + (size_t)row * 1024 + a * 64);
      int sw = 4 * (j & 15);
      short* rowp = &S.at.klds[j * 512];
      #pragma unroll
      for (int b = 0; b < 8; ++b) {
        short8 val = src[b];
        int d0 = a * 64 + b * 8;
        *(short4*)&rowp[(d0    ) ^ sw] = *(const short4*)&val;
        *(short4*)&rowp[(d0 + 4) ^ sw] = *((const short4*)&val + 1);
      }
    }
    __syncthreads();

    int jk = lane & 31, half = lane >> 5;
    // scores + softmax, wave handles heads wv_ and wv_+4
    #pragma unroll
    for (int hp = 0; hp < 2; ++hp) {
      int h = wv_ + hp * 4;
      int dbase = h * 64 + half * 32;
      float qv[32];
      {
        const float4* qs = (const float4*)(qb + rb + dbase);
        #pragma unroll
        for (int b = 0; b < 8; ++b) {
          float4 f = qs[b];
          qv[b*4+0] = f.x; qv[b*4+1] = f.y; qv[b*4+2] = f.z; qv[b*4+3] = f.w;
        }
      }
      float s = 0.f;
      int sw = 4 * (jk & 15);
      const short* krow = &S.at.klds[jk * 512];
      #pragma unroll
      for (int i4 = 0; i4 < 8; ++i4) {
        short4 kk = *(const short4*)&krow[(dbase + i4 * 4) ^ sw];
        s += qv[i4*4+0] * bf2f_bits(kk.x) + qv[i4*4+1] * bf2f_bits(kk.y)
           + qv[i4*4+2] * bf2f_bits(kk.z) + qv[i4*4+3] * bf2f_bits(kk.w);
      }
      s += __shfl_xor(s, 32);
      s *= 0.125f;
      float mx = s;
      #pragma unroll
      for (int o = 16; o > 0; o >>= 1) mx = fmaxf(mx, __shfl_xor(mx, o));
      float pp = expf(s - mx);
      float l = pp;
      #pragma unroll
      for (int o = 16; o > 0; o >>= 1) l += __shfl_xor(l, o);
      pp *= (1.0f / l);
      if (half == 0) S.at.plds[h * 32 + jk] = pp;   // intra-wave only
    }
    // ctx: lane = dim
    #pragma unroll
    for (int hp = 0; hp < 2; ++hp) {
      int h = wv_ + hp * 4;
      float pv[32];
      #pragma unroll
      for (int b = 0; b < 8; ++b) {
        float4 f = *(const float4*)&S.at.plds[h * 32 + b * 4];
        pv[b*4+0] = f.x; pv[b*4+1] = f.y; pv[b*4+2] = f.z; pv[b*4+3] = f.w;
      }
      int off = 512 + h * 64 + lane;
      float acc = 0.f;
      #pragma unroll
      for (int j = 0; j < NN_K; ++j)
        acc += pv[j] * bf2f_bits(kv[(size_t)S.at.sidx[j] * 1024 + off]);
      ctx_bf[rb + h * 64 + lane] = (short)f2bf(acc);
    }
  }

  //========================= Phase D: out =========================
  grid_barrier(&bar[2]);
  if (blk < 256) {
    int r0 = (blk >> 3) << 6, c0 = (blk & 7) << 6;
    gemm64(ctx_bf, w_bf + (size_t)3 * 262144, bo, outp, nullptr, 512, 0,
           N, r0, c0, true, S.gm.sA, S.gm.sB);
  }
}

// ---------------------------------------------------------------------------
extern "C" void kernel_launch(void* const* d_in, const int* in_sizes, int n_in,
                              void* d_out, int out_size, void* d_ws, size_t ws_size,
                              hipStream_t stream) {
  const float* x       = (const float*)d_in[0];
  const float* coords9 = (const float*)d_in[1];
  const float* prompt  = (const float*)d_in[2];
  const float* pos_w1  = (const float*)d_in[3];
  const float* pos_b1  = (const float*)d_in[4];
  const float* ln_g    = (const float*)d_in[5];
  const float* ln_b    = (const float*)d_in[6];
  const float* wq      = (const float*)d_in[7];
  const float* wk      = (const float*)d_in[8];
  const float* wv      = (const float*)d_in[9];
  const float* bq      = (const float*)d_in[10];
  const float* bk      = (const float*)d_in[11];
  const float* bv      = (const float*)d_in[12];
  const float* wo      = (const float*)d_in[13];
  const float* bo      = (const float*)d_in[14];

  int N = in_sizes[1] / 9;                       // 2000
  int Mpad = (N + 127) & ~127;                   // 2048
  size_t PE = (size_t)Mpad * E_DIM;

  char* p = (char*)d_ws;
  short* pos_bf = (short*)p; p += PE * 2;                      // 2 MB
  short* w_bf   = (short*)p; p += (size_t)4 * 512 * 512 * 2;   // 2 MB
  float* qb     = (float*)p; p += PE * 4;                      // 4 MB
  short* kv_bf  = (short*)p; p += PE * 2 * 2;                  // 4 MB (k|v)
  short* ctx_bf = (short*)p; p += PE * 2;                      // 2 MB
  int*   topkb  = (int*)p;   p += (size_t)N * NN_K * 4;        // 256 KB
  p = (char*)(((uintptr_t)p + 255) & ~(uintptr_t)255);
  unsigned* bar = (unsigned*)p;                                // 3 counters

  hipMemsetAsync(bar, 0, 64, stream);
  mega_kernel<<<NBLK, 256, 0, stream>>>(
      x, coords9, prompt, pos_w1, pos_b1, ln_g, ln_b,
      wq, wk, wv, wo, bq, bk, bv, bo,
      w_bf, pos_bf, topkb, qb, kv_bf, ctx_bf, (float*)d_out,
      bar, N, Mpad);
}

// Round 8
// 429.694 us; speedup vs baseline: 1.0019x; 1.0019x over previous
//
#include <hip/hip_runtime.h>
#include <math.h>

#define NN_K 32
#define E_DIM 512
#define CLAMP_V 10000.0f
#define NBLK 768            // 3 blocks/CU x 256 CUs: co-resident by construction

typedef __attribute__((ext_vector_type(8))) short short8;
typedef __attribute__((ext_vector_type(4))) float f32x4;

// bf16 RTNE, bit-level
__device__ __forceinline__ unsigned short f2bf(float x) {
  unsigned u = __float_as_uint(x);
  unsigned r = u + 0x7fffu + ((u >> 16) & 1u);
  return (unsigned short)(r >> 16);
}
__device__ __forceinline__ float bf2f_bits(short h) {
  return __uint_as_float(((unsigned)(unsigned short)h) << 16);
}
__device__ __forceinline__ void async16(const void* g, void* l) {
  __builtin_amdgcn_global_load_lds((const __attribute__((address_space(1))) void*)g,
                                   (__attribute__((address_space(3))) void*)l, 16, 0, 0);
}

// Grid barrier v2: arrive with ONE device-scope atomicAdd; poll with coherent
// atomic LOADS (not RMW — R7's atomicAdd(cnt,0) poll serialized 768 blocks at
// the LLC atomic unit: 6.7% VALUBusy over 356us = ~110us idle per barrier).
// s_sleep(8) ~= 512cyc backoff. Counters zeroed by hipMemsetAsync node.
__device__ __forceinline__ void grid_barrier(unsigned* cnt) {
  __syncthreads();   // also drains vmcnt/lgkm for every thread (compiler)
  if (threadIdx.x == 0) {
    __threadfence();
    atomicAdd(cnt, 1u);
    while (__hip_atomic_load(cnt, __ATOMIC_RELAXED, __HIP_MEMORY_SCOPE_AGENT) < NBLK)
      __builtin_amdgcn_s_sleep(8);
    __threadfence();
  }
  __syncthreads();
}

// ---------------------------------------------------------------------------
// 64x64-tile bf16 MFMA GEMM step (BK=32, 16 iters, dbuf vmcnt(2) pipeline).
// 4 waves, each computing a 32x32 quadrant (2x2 16x16x32 MFMAs / iter).
// ---------------------------------------------------------------------------
__device__ __forceinline__ void gemm64(
    const short* __restrict__ A, const short* __restrict__ W,
    const float* __restrict__ bias,
    float* __restrict__ outf, short* __restrict__ outb,
    int out_ld, int out_c0, int Mstore, int row0, int col0, bool doClamp,
    short (*sA)[2048], short (*sB)[2048])
{
  int t = threadIdx.x;
  int cr = t >> 2, ck = (t & 3) << 3;
  const short* gA = A + (size_t)(row0 + cr) * 512 + ck;
  const short* gB = W + (size_t)(col0 + cr) * 512 + ck;
  int lo = t * 8;
  int lane = t & 63, w = t >> 6;
  int wm = (w & 1) << 5, wn = (w >> 1) << 5;
  int lr = lane & 15, lq = lane >> 4;

#define STG(tt, b) { async16(gA + (tt) * 32, &sA[b][lo]); \
                     async16(gB + (tt) * 32, &sB[b][lo]); }
  STG(0, 0);
  STG(1, 1);

  f32x4 acc[2][2];
  #pragma unroll
  for (int i = 0; i < 2; ++i)
    #pragma unroll
    for (int j = 0; j < 2; ++j)
      acc[i][j] = (f32x4){0.f, 0.f, 0.f, 0.f};

  #pragma unroll
  for (int it = 0; it < 16; ++it) {
    int cur = it & 1;
    if (it == 15) asm volatile("s_waitcnt vmcnt(0)\ns_barrier" ::: "memory");
    else          asm volatile("s_waitcnt vmcnt(2)\ns_barrier" ::: "memory");

    short8 af[2], bfr[2];
    #pragma unroll
    for (int i = 0; i < 2; ++i) {
      af[i]  = *(const short8*)&sA[cur][(wm + (i << 4) + lr) * 32 + (lq << 3)];
      bfr[i] = *(const short8*)&sB[cur][(wn + (i << 4) + lr) * 32 + (lq << 3)];
    }
    #pragma unroll
    for (int i = 0; i < 2; ++i)
      #pragma unroll
      for (int j = 0; j < 2; ++j)
        acc[i][j] = __builtin_amdgcn_mfma_f32_16x16x32_bf16(af[i], bfr[j], acc[i][j], 0, 0, 0);

    asm volatile("s_waitcnt lgkmcnt(0)\ns_barrier" ::: "memory");
    if (it + 2 < 16) STG(it + 2, cur);
  }
#undef STG

  #pragma unroll
  for (int j = 0; j < 2; ++j) {
    int gcol = col0 + wn + (j << 4) + lr;
    float bv_ = bias[gcol];
    #pragma unroll
    for (int i = 0; i < 2; ++i) {
      #pragma unroll
      for (int rr = 0; rr < 4; ++rr) {
        int grow = row0 + wm + (i << 4) + (lq << 2) + rr;
        if (grow < Mstore) {
          float v = acc[i][j][rr] + bv_;
          if (doClamp) {
            v = isnan(v) ? 0.0f : v;
            v = fminf(fmaxf(v, -CLAMP_V), CLAMP_V);
          }
          if (outf) outf[(size_t)grow * 512 + gcol] = v;
          else      outb[(size_t)grow * out_ld + out_c0 + gcol] = (short)f2bf(v);
        }
      }
    }
  }
}

// ---------------------------------------------------------------------------
// Mega-kernel: A(front) -> B(qkv) -> C(attn) -> D(out) with grid barriers.
// ---------------------------------------------------------------------------
__global__ __launch_bounds__(256, 3) void mega_kernel(
    const float* __restrict__ x, const float* __restrict__ coords9,
    const float* __restrict__ prompt,
    const float* __restrict__ w1, const float* __restrict__ b1,
    const float* __restrict__ ln_g, const float* __restrict__ ln_b,
    const float* __restrict__ wq, const float* __restrict__ wk,
    const float* __restrict__ wv, const float* __restrict__ wo,
    const float* __restrict__ bq, const float* __restrict__ bk,
    const float* __restrict__ bv, const float* __restrict__ bo,
    short* __restrict__ w_bf, short* __restrict__ pos_bf,
    int* __restrict__ topkb, float* __restrict__ qb, short* __restrict__ kv,
    short* __restrict__ ctx_bf, float* __restrict__ outp,
    unsigned* __restrict__ bar, int N, int Mpad)
{
  __shared__ union {
    struct { float red[8]; } pos;
    struct { unsigned hist[256]; unsigned waveSums[4];
             unsigned sel_bin, sel_rem, cnt, tcnt; unsigned tie[2048]; } tk;
    struct { short sA[2][2048]; short sB[2][2048]; } gm;           // 16 KB
    struct { short klds[16384]; int sidx[NN_K]; float plds[256]; } at; // 33.9 KB
  } S;

  int blk = blockIdx.x, t = threadIdx.x;
  int lane = t & 63, wv_ = t >> 6;

  //========================= Phase A: front =========================
  // wconv: 262144 float4s, grid-stride
  #pragma unroll
  for (int i = 0; i < 2; ++i) {
    int v = blk * 256 + t + i * (NBLK * 256);
    if (v < 262144) {
      int m = v >> 16, e = v & 0xffff;
      const float* src = m == 0 ? wq : (m == 1 ? wk : (m == 2 ? wv : wo));
      float4 f = ((const float4*)src)[e];
      short4 h;
      h.x = (short)f2bf(f.x); h.y = (short)f2bf(f.y);
      h.z = (short)f2bf(f.z); h.w = (short)f2bf(f.w);
      ((short4*)w_bf)[v] = h;
    }
  }
  // pos: up to 3 rows per block
  for (int r = 0; r < 3; ++r) {
    int n = blk + r * NBLK;
    if (n >= Mpad) break;
    size_t rb = (size_t)n * E_DIM;
    if (n >= N) {
      for (int j = t; j < E_DIM; j += 256) pos_bf[rb + j] = 0;
      continue;
    }
    __syncthreads();
    float g = 0.f, d = 0.f;
    if (t < 128) {
      const float* c9 = coords9 + n * 9;
      float c0 = (c9[0] + c9[3] + c9[6]) / 3.0f;
      float c1 = (c9[1] + c9[4] + c9[7]) / 3.0f;
      float c2 = (c9[2] + c9[5] + c9[8]) / 3.0f;
      float pre = c0 * w1[t*3+0] + c1 * w1[t*3+1] + c2 * w1[t*3+2] + b1[t];
      g = 0.5f * pre * (1.0f + erff(pre * 0.70710678118654752440f));
      float s = g;
      #pragma unroll
      for (int o = 32; o > 0; o >>= 1) s += __shfl_xor(s, o);
      if ((t & 63) == 0) S.pos.red[t >> 6] = s;
    }
    __syncthreads();
    if (t < 128) {
      float mu = (S.pos.red[0] + S.pos.red[1]) * (1.0f / 128.0f);
      d = g - mu;
      float s2 = d * d;
      #pragma unroll
      for (int o = 32; o > 0; o >>= 1) s2 += __shfl_xor(s2, o);
      if ((t & 63) == 0) S.pos.red[2 + (t >> 6)] = s2;
    }
    __syncthreads();
    if (t < 128) {
      float var = (S.pos.red[2] + S.pos.red[3]) * (1.0f / 128.0f);
      float y = d * rsqrtf(var + 1e-5f) * ln_g[t] + ln_b[t];
      pos_bf[rb + 384 + t] = (short)f2bf(y);
    }
    for (int j = t; j < 384; j += 256)
      pos_bf[rb + j] = (short)f2bf(x[rb + j] + prompt[j]);
  }
  // topk: up to 3 rows per block, centroids computed inline (bit-identical)
  for (int r = 0; r < 3; ++r) {
    int n = blk + r * NBLK;
    if (n >= N) break;
    __syncthreads();
    const float* cn = coords9 + n * 9;
    float cx = (cn[0] + cn[3] + cn[6]) / 3.0f;
    float cy = (cn[1] + cn[4] + cn[7]) / 3.0f;
    float cz = (cn[2] + cn[5] + cn[8]) / 3.0f;
    unsigned bits[8];
    #pragma unroll
    for (int rr = 0; rr < 8; ++rr) {
      int m = t + (rr << 8);
      unsigned b = 0xFFFFFFFFu;
      if (m < N) {
        const float* cm = coords9 + m * 9;
        float mx_ = (cm[0] + cm[3] + cm[6]) / 3.0f;
        float my_ = (cm[1] + cm[4] + cm[7]) / 3.0f;
        float mz_ = (cm[2] + cm[5] + cm[8]) / 3.0f;
        float dx = cx - mx_, dy = cy - my_, dz = cz - mz_;
        b = __float_as_uint(sqrtf(dx*dx + dy*dy + dz*dz));
      }
      bits[rr] = b;
    }
    unsigned prefix = 0, K_rem = NN_K;
    #pragma unroll
    for (int p = 0; p < 4; ++p) {
      int shift = 24 - 8 * p;
      unsigned high_mask = (p == 0) ? 0u : (0xFFFFFFFFu << (8 * (4 - p)));
      S.tk.hist[t] = 0;
      __syncthreads();
      #pragma unroll
      for (int rr = 0; rr < 8; ++rr)
        if ((bits[rr] & high_mask) == prefix)
          atomicAdd(&S.tk.hist[(bits[rr] >> shift) & 255], 1u);
      __syncthreads();
      unsigned h = S.tk.hist[t];
      unsigned scan = h;
      #pragma unroll
      for (int o = 1; o < 64; o <<= 1) {
        unsigned u = __shfl_up(scan, o);
        if (lane >= o) scan += u;
      }
      if (lane == 63) S.tk.waveSums[wv_] = scan;
      __syncthreads();
      unsigned off = 0;
      for (int w2 = 0; w2 < wv_; ++w2) off += S.tk.waveSums[w2];
      scan += off;
      if (scan >= K_rem && (scan - h) < K_rem) {
        S.tk.sel_bin = (unsigned)t;
        S.tk.sel_rem = K_rem - (scan - h);
      }
      __syncthreads();
      prefix |= S.tk.sel_bin << shift;
      K_rem = S.tk.sel_rem;
      __syncthreads();
    }
    unsigned T = prefix;
    if (t == 0) { S.tk.cnt = 0; S.tk.tcnt = 0; }
    __syncthreads();
    #pragma unroll
    for (int rr = 0; rr < 8; ++rr) {
      int m = t + (rr << 8);
      if (m < N) {
        if (bits[rr] < T) {
          unsigned slot = atomicAdd(&S.tk.cnt, 1u);
          topkb[n * NN_K + slot] = m;
        } else if (bits[rr] == T) {
          unsigned tp = atomicAdd(&S.tk.tcnt, 1u);
          S.tk.tie[tp] = (unsigned)m;
        }
      }
    }
    __syncthreads();
    if (t == 0) {
      unsigned base = S.tk.cnt, need = K_rem;
      for (unsigned it = 0; it < need; ++it) {
        unsigned best = 0xFFFFFFFFu, bj = 0;
        for (unsigned j = 0; j < S.tk.tcnt; ++j)
          if (S.tk.tie[j] < best) { best = S.tk.tie[j]; bj = j; }
        topkb[n * NN_K + base + it] = (int)best;
        S.tk.tie[bj] = 0xFFFFFFFFu;
      }
    }
  }

  //========================= Phase B: qkv =========================
  grid_barrier(&bar[0]);
  {
    int sel = blk / 256, rem = blk & 255;          // 768 = 3 x (32x8) tiles
    int r0 = (rem >> 3) << 6, c0 = (rem & 7) << 6;
    const short* W = w_bf + (size_t)sel * 262144;
    if (sel == 0)
      gemm64(pos_bf, W, bq, qb, nullptr, 512, 0, Mpad, r0, c0, false, S.gm.sA, S.gm.sB);
    else if (sel == 1)
      gemm64(pos_bf, W, bk, nullptr, kv, 1024, 0, Mpad, r0, c0, false, S.gm.sA, S.gm.sB);
    else
      gemm64(pos_bf, W, bv, nullptr, kv, 1024, 512, Mpad, r0, c0, false, S.gm.sA, S.gm.sB);
  }

  //========================= Phase C: attn =========================
  grid_barrier(&bar[1]);
  for (int r = 0; r < 3; ++r) {
    int n = blk + r * NBLK;
    if (n >= Mpad) break;
    size_t rb = (size_t)n * E_DIM;
    __syncthreads();                                // klds reuse across r
    if (n >= N) {
      for (int j = t; j < E_DIM; j += 256) ctx_bf[rb + j] = 0;
      continue;
    }
    if (t < NN_K) S.at.sidx[t] = topkb[n * NN_K + t];
    {
      // staging remap: j=t&31 row, c=t>>5 chunk -> write banks
      // (b*8+sel)^2*(j&15): 16 banks x 4-way (was 8-way in R7 -> 8.2M conflicts)
      int j = t & 31, c = t >> 5;
      int row = topkb[n * NN_K + j];
      const short8* src = (const short8*)(kv + (size_t)row * 1024 + c * 64);
      int sw = 4 * (j & 15);
      short* rowp = &S.at.klds[j * 512];
      #pragma unroll
      for (int b = 0; b < 8; ++b) {
        short8 val = src[b];
        int d0 = c * 64 + b * 8;
        *(short4*)&rowp[(d0    ) ^ sw] = *(const short4*)&val;
        *(short4*)&rowp[(d0 + 4) ^ sw] = *((const short4*)&val + 1);
      }
    }
    __syncthreads();

    int jk = lane & 31, half = lane >> 5;
    // scores + softmax, wave handles heads wv_ and wv_+4
    #pragma unroll
    for (int hp = 0; hp < 2; ++hp) {
      int h = wv_ + hp * 4;
      int dbase = h * 64 + half * 32;
      float qv[32];
      {
        const float4* qs = (const float4*)(qb + rb + dbase);
        #pragma unroll
        for (int b = 0; b < 8; ++b) {
          float4 f = qs[b];
          qv[b*4+0] = f.x; qv[b*4+1] = f.y; qv[b*4+2] = f.z; qv[b*4+3] = f.w;
        }
      }
      float s = 0.f;
      int sw = 4 * (jk & 15);
      const short* krow = &S.at.klds[jk * 512];
      #pragma unroll
      for (int i4 = 0; i4 < 8; ++i4) {
        short4 kk = *(const short4*)&krow[(dbase + i4 * 4) ^ sw];
        s += qv[i4*4+0] * bf2f_bits(kk.x) + qv[i4*4+1] * bf2f_bits(kk.y)
           + qv[i4*4+2] * bf2f_bits(kk.z) + qv[i4*4+3] * bf2f_bits(kk.w);
      }
      s += __shfl_xor(s, 32);
      s *= 0.125f;
      float mx = s;
      #pragma unroll
      for (int o = 16; o > 0; o >>= 1) mx = fmaxf(mx, __shfl_xor(mx, o));
      float pp = expf(s - mx);
      float l = pp;
      #pragma unroll
      for (int o = 16; o > 0; o >>= 1) l += __shfl_xor(l, o);
      pp *= (1.0f / l);
      if (half == 0) S.at.plds[h * 32 + jk] = pp;   // intra-wave only
    }
    // ctx: lane = dim
    #pragma unroll
    for (int hp = 0; hp < 2; ++hp) {
      int h = wv_ + hp * 4;
      float pv[32];
      #pragma unroll
      for (int b = 0; b < 8; ++b) {
        float4 f = *(const float4*)&S.at.plds[h * 32 + b * 4];
        pv[b*4+0] = f.x; pv[b*4+1] = f.y; pv[b*4+2] = f.z; pv[b*4+3] = f.w;
      }
      int off = 512 + h * 64 + lane;
      float acc = 0.f;
      #pragma unroll
      for (int j = 0; j < NN_K; ++j)
        acc += pv[j] * bf2f_bits(kv[(size_t)S.at.sidx[j] * 1024 + off]);
      ctx_bf[rb + h * 64 + lane] = (short)f2bf(acc);
    }
  }

  //========================= Phase D: out =========================
  grid_barrier(&bar[2]);
  if (blk < 256) {
    int r0 = (blk >> 3) << 6, c0 = (blk & 7) << 6;
    gemm64(ctx_bf, w_bf + (size_t)3 * 262144, bo, outp, nullptr, 512, 0,
           N, r0, c0, true, S.gm.sA, S.gm.sB);
  }
}

// ---------------------------------------------------------------------------
extern "C" void kernel_launch(void* const* d_in, const int* in_sizes, int n_in,
                              void* d_out, int out_size, void* d_ws, size_t ws_size,
                              hipStream_t stream) {
  const float* x       = (const float*)d_in[0];
  const float* coords9 = (const float*)d_in[1];
  const float* prompt  = (const float*)d_in[2];
  const float* pos_w1  = (const float*)d_in[3];
  const float* pos_b1  = (const float*)d_in[4];
  const float* ln_g    = (const float*)d_in[5];
  const float* ln_b    = (const float*)d_in[6];
  const float* wq      = (const float*)d_in[7];
  const float* wk      = (const float*)d_in[8];
  const float* wv      = (const float*)d_in[9];
  const float* bq      = (const float*)d_in[10];
  const float* bk      = (const float*)d_in[11];
  const float* bv      = (const float*)d_in[12];
  const float* wo      = (const float*)d_in[13];
  const float* bo      = (const float*)d_in[14];

  int N = in_sizes[1] / 9;                       // 2000
  int Mpad = (N + 127) & ~127;                   // 2048
  size_t PE = (size_t)Mpad * E_DIM;

  char* p = (char*)d_ws;
  short* pos_bf = (short*)p; p += PE * 2;                      // 2 MB
  short* w_bf   = (short*)p; p += (size_t)4 * 512 * 512 * 2;   // 2 MB
  float* qb     = (float*)p; p += PE * 4;                      // 4 MB
  short* kv_bf  = (short*)p; p += PE * 2 * 2;                  // 4 MB (k|v)
  short* ctx_bf = (short*)p; p += PE * 2;                      // 2 MB
  int*   topkb  = (int*)p;   p += (size_t)N * NN_K * 4;        // 256 KB
  p = (char*)(((uintptr_t)p + 255) & ~(uintptr_t)255);
  unsigned* bar = (unsigned*)p;                                // 3 counters

  hipMemsetAsync(bar, 0, 64, stream);
  mega_kernel<<<NBLK, 256, 0, stream>>>(
      x, coords9, prompt, pos_w1, pos_b1, ln_g, ln_b,
      wq, wk, wv, wo, bq, bk, bv, bo,
      w_bf, pos_bf, topkb, qb, kv_bf, ctx_bf, (float*)d_out,
      bar, N, Mpad);
}

// Round 9
// 154.267 us; speedup vs baseline: 2.7907x; 2.7854x over previous
//
#include <hip/hip_runtime.h>
#include <math.h>

#define NN_K 32
#define E_DIM 512
#define CLAMP_V 10000.0f

typedef __attribute__((ext_vector_type(8))) short short8;
typedef __attribute__((ext_vector_type(4))) float f32x4;

// bf16 RTNE, bit-level
__device__ __forceinline__ unsigned short f2bf(float x) {
  unsigned u = __float_as_uint(x);
  unsigned r = u + 0x7fffu + ((u >> 16) & 1u);
  return (unsigned short)(r >> 16);
}
__device__ __forceinline__ float bf2f_bits(short h) {
  return __uint_as_float(((unsigned)(unsigned short)h) << 16);
}

__device__ __forceinline__ void async16(const void* g, void* l) {
  __builtin_amdgcn_global_load_lds((const __attribute__((address_space(1))) void*)g,
                                   (__attribute__((address_space(3))) void*)l, 16, 0, 0);
}

// ---------------------------------------------------------------------------
// Kernel 1 (fused front): grid-partitioned independent phases.
//   blocks [0,256):        wconv  — 4 weight matrices fp32 -> bf16
//   blocks [256,2304):     pos    — centroid+Linear(3,128)+GELU+LN+concat
//   blocks [2304,4304):    topk   — radix select over candidate centroids
//                                   (centroids recomputed from coords9 —
//                                   bit-identical to pos's, no dependency)
// ---------------------------------------------------------------------------
__global__ __launch_bounds__(256) void front_kernel(
    const float* __restrict__ x, const float* __restrict__ coords9,
    const float* __restrict__ prompt,
    const float* __restrict__ w1, const float* __restrict__ b1,
    const float* __restrict__ ln_g, const float* __restrict__ ln_b,
    const float* __restrict__ wq, const float* __restrict__ wk,
    const float* __restrict__ wv, const float* __restrict__ wo,
    short* __restrict__ w_bf, short* __restrict__ pos_bf,
    int* __restrict__ topk, int N, int Mpad)
{
  int blk = blockIdx.x;
  int t = threadIdx.x;

  if (blk < 256) {
    #pragma unroll
    for (int i = 0; i < 4; ++i) {
      int v = blk * 256 + t + i * 65536;
      int m = v >> 16;
      int e = v & 0xffff;
      const float* src = m == 0 ? wq : (m == 1 ? wk : (m == 2 ? wv : wo));
      float4 f = ((const float4*)src)[e];
      short4 h;
      h.x = (short)f2bf(f.x); h.y = (short)f2bf(f.y);
      h.z = (short)f2bf(f.z); h.w = (short)f2bf(f.w);
      ((short4*)w_bf)[v] = h;
    }
    return;
  }

  if (blk < 2304) {
    int n = blk - 256;
    size_t rb = (size_t)n * E_DIM;
    if (n >= N) {
      #pragma unroll
      for (int j = t; j < E_DIM; j += 256) pos_bf[rb + j] = 0;
      return;
    }
    __shared__ float red[4];
    float g = 0.f;
    if (t < 128) {
      const float* c9 = coords9 + n * 9;
      float c0 = (c9[0] + c9[3] + c9[6]) / 3.0f;
      float c1 = (c9[1] + c9[4] + c9[7]) / 3.0f;
      float c2 = (c9[2] + c9[5] + c9[8]) / 3.0f;
      float pre = c0 * w1[t*3+0] + c1 * w1[t*3+1] + c2 * w1[t*3+2] + b1[t];
      g = 0.5f * pre * (1.0f + erff(pre * 0.70710678118654752440f));
      float s = g;
      #pragma unroll
      for (int o = 32; o > 0; o >>= 1) s += __shfl_xor(s, o);
      if ((t & 63) == 0) red[t >> 6] = s;
    }
    __syncthreads();
    float mu = (red[0] + red[1]) * (1.0f / 128.0f);
    float d = g - mu;
    if (t < 128) {
      float s2 = d * d;
      #pragma unroll
      for (int o = 32; o > 0; o >>= 1) s2 += __shfl_xor(s2, o);
      if ((t & 63) == 0) red[2 + (t >> 6)] = s2;
    }
    __syncthreads();
    if (t < 128) {
      float var = (red[2] + red[3]) * (1.0f / 128.0f);
      float y = d * rsqrtf(var + 1e-5f) * ln_g[t] + ln_b[t];
      pos_bf[rb + 384 + t] = (short)f2bf(y);
    }
    #pragma unroll
    for (int j = t; j < 384; j += 256)
      pos_bf[rb + j] = (short)f2bf(x[rb + j] + prompt[j]);
    return;
  }

  // ---- topk: 4-pass radix select; centroids computed inline ----
  {
    __shared__ unsigned hist[256];
    __shared__ unsigned waveSums[4];
    __shared__ unsigned sel_bin, sel_rem;
    __shared__ unsigned cnt, tcnt;
    __shared__ unsigned tie[2048];

    int n = blk - 2304;
    int lane = t & 63, wid = t >> 6;
    const float* cn = coords9 + n * 9;
    float cx = (cn[0] + cn[3] + cn[6]) / 3.0f;
    float cy = (cn[1] + cn[4] + cn[7]) / 3.0f;
    float cz = (cn[2] + cn[5] + cn[8]) / 3.0f;

    unsigned bits[8];
    #pragma unroll
    for (int r = 0; r < 8; ++r) {
      int m = t + (r << 8);
      unsigned b = 0xFFFFFFFFu;
      if (m < N) {
        const float* cm = coords9 + m * 9;
        float mx_ = (cm[0] + cm[3] + cm[6]) / 3.0f;
        float my_ = (cm[1] + cm[4] + cm[7]) / 3.0f;
        float mz_ = (cm[2] + cm[5] + cm[8]) / 3.0f;
        float dx = cx - mx_, dy = cy - my_, dz = cz - mz_;
        float dist = sqrtf(dx*dx + dy*dy + dz*dz);
        b = __float_as_uint(dist);
      }
      bits[r] = b;
    }

    unsigned prefix = 0;
    unsigned K_rem = NN_K;
    #pragma unroll
    for (int p = 0; p < 4; ++p) {
      int shift = 24 - 8 * p;
      unsigned high_mask = (p == 0) ? 0u : (0xFFFFFFFFu << (8 * (4 - p)));
      hist[t] = 0;
      __syncthreads();
      #pragma unroll
      for (int r = 0; r < 8; ++r) {
        if ((bits[r] & high_mask) == prefix)
          atomicAdd(&hist[(bits[r] >> shift) & 255], 1u);
      }
      __syncthreads();
      unsigned h = hist[t];
      unsigned scan = h;
      #pragma unroll
      for (int o = 1; o < 64; o <<= 1) {
        unsigned u = __shfl_up(scan, o);
        if (lane >= o) scan += u;
      }
      if (lane == 63) waveSums[wid] = scan;
      __syncthreads();
      unsigned off = 0;
      for (int w = 0; w < wid; ++w) off += waveSums[w];
      scan += off;
      if (scan >= K_rem && (scan - h) < K_rem) {
        sel_bin = (unsigned)t;
        sel_rem = K_rem - (scan - h);
      }
      __syncthreads();
      prefix |= sel_bin << shift;
      K_rem = sel_rem;
      __syncthreads();
    }

    unsigned T = prefix;
    if (t == 0) { cnt = 0; tcnt = 0; }
    __syncthreads();
    #pragma unroll
    for (int r = 0; r < 8; ++r) {
      int m = t + (r << 8);
      if (m < N) {
        if (bits[r] < T) {
          unsigned slot = atomicAdd(&cnt, 1u);
          topk[n * NN_K + slot] = m;
        } else if (bits[r] == T) {
          unsigned tp = atomicAdd(&tcnt, 1u);
          tie[tp] = (unsigned)m;
        }
      }
    }
    __syncthreads();
    if (t == 0) {
      unsigned base = cnt;
      unsigned need = K_rem;
      for (unsigned it = 0; it < need; ++it) {
        unsigned best = 0xFFFFFFFFu, bj = 0;
        for (unsigned j = 0; j < tcnt; ++j)
          if (tie[j] < best) { best = tie[j]; bj = j; }
        topk[n * NN_K + base + it] = (int)best;
        tie[bj] = 0xFFFFFFFFu;
      }
    }
  }
}

// ---------------------------------------------------------------------------
// bf16 MFMA GEMM, 64x128 tile, double-buffered vmcnt(3)+s_barrier pipeline.
// 256 thr = 4 waves; wave w computes 64 rows x 32 cols (acc 4x2).
// ---------------------------------------------------------------------------
__device__ __forceinline__ void gemm_core(
    const short* __restrict__ A, const short* __restrict__ W,
    const float* __restrict__ bias,
    float* __restrict__ outf, short* __restrict__ outb,
    int out_ld, int out_c0,
    int M, int row0, int col0, bool doClamp)
{
  __shared__ short sA[2][64 * 32], sB[2][128 * 32];
  int tid = threadIdx.x;
  int cr = tid >> 2;
  int ck = (tid & 3) << 3;
  const short* gA = A + (size_t)(row0 + cr) * 512 + ck;
  const short* gB = W + (size_t)(col0 + cr) * 512 + ck;
  int lo = tid * 8, loB1 = (tid + 256) * 8;
  const size_t rstep = (size_t)64 * 512;

  int lane = tid & 63, wv_ = tid >> 6;
  int wn = wv_ << 5;
  int lr = lane & 15, lq = lane >> 4;

#define STAGE(t, b) do { \
    async16(gA + (t) * 32,         &sA[b][lo]); \
    async16(gB + (t) * 32,         &sB[b][lo]); \
    async16(gB + (t) * 32 + rstep, &sB[b][loB1]); } while (0)

  STAGE(0, 0);
  STAGE(1, 1);

  f32x4 acc[4][2];
  #pragma unroll
  for (int i = 0; i < 4; ++i)
    #pragma unroll
    for (int j = 0; j < 2; ++j)
      acc[i][j] = (f32x4){0.f, 0.f, 0.f, 0.f};

  #pragma unroll
  for (int it = 0; it < 16; ++it) {
    int cur = it & 1;
    if (it == 15) asm volatile("s_waitcnt vmcnt(0)\ns_barrier" ::: "memory");
    else          asm volatile("s_waitcnt vmcnt(3)\ns_barrier" ::: "memory");

    short8 af[4], bf[2];
    #pragma unroll
    for (int i = 0; i < 4; ++i)
      af[i] = *(const short8*)&sA[cur][((i << 4) + lr) * 32 + (lq << 3)];
    #pragma unroll
    for (int j = 0; j < 2; ++j)
      bf[j] = *(const short8*)&sB[cur][(wn + (j << 4) + lr) * 32 + (lq << 3)];
    #pragma unroll
    for (int i = 0; i < 4; ++i)
      #pragma unroll
      for (int j = 0; j < 2; ++j)
        acc[i][j] = __builtin_amdgcn_mfma_f32_16x16x32_bf16(af[i], bf[j], acc[i][j], 0, 0, 0);

    asm volatile("s_waitcnt lgkmcnt(0)\ns_barrier" ::: "memory");
    if (it + 2 < 16) STAGE(it + 2, cur);
  }
#undef STAGE

  #pragma unroll
  for (int j = 0; j < 2; ++j) {
    int gcol = col0 + wn + (j << 4) + lr;
    float bv_ = bias[gcol];
    #pragma unroll
    for (int i = 0; i < 4; ++i) {
      #pragma unroll
      for (int r = 0; r < 4; ++r) {
        int grow = row0 + (i << 4) + (lq << 2) + r;
        if (grow < M) {
          float v = acc[i][j][r] + bv_;
          if (doClamp) {
            v = isnan(v) ? 0.0f : v;
            v = fminf(fmaxf(v, -CLAMP_V), CLAMP_V);
          }
          if (outf) outf[(size_t)grow * 512 + gcol] = v;
          else      outb[(size_t)grow * out_ld + out_c0 + gcol] = (short)f2bf(v);
        }
      }
    }
  }
}

__global__ __launch_bounds__(256) void qkv_mfma(
    const short* __restrict__ A, const short* __restrict__ Wb,
    const float* __restrict__ bq, const float* __restrict__ bk, const float* __restrict__ bv,
    float* __restrict__ qb, short* __restrict__ kv, int M)
{
  int sel = blockIdx.y >> 2;
  int nblk = blockIdx.y & 3;
  int r0 = blockIdx.x * 64, c0 = nblk * 128;
  if (sel == 0)
    gemm_core(A, Wb, bq, qb, nullptr, 512, 0, M, r0, c0, false);
  else if (sel == 1)
    gemm_core(A, Wb + 262144, bk, nullptr, kv, 1024, 0, M, r0, c0, false);
  else
    gemm_core(A, Wb + 2 * 262144, bv, nullptr, kv, 1024, 512, M, r0, c0, false);
}

__global__ __launch_bounds__(256) void out_mfma(
    const short* __restrict__ A, const short* __restrict__ Wb,
    const float* __restrict__ bias, float* __restrict__ out, int M)
{
  gemm_core(A, Wb + (size_t)3 * 262144, bias, out, nullptr, 512, 0, M,
            blockIdx.x * 64, blockIdx.y * 128, true);
}

// ---------------------------------------------------------------------------
// Kernel 3: sparse top-K attention, lane-per-key scores, b64 LDS reads.
// Staging remap (vs R6): row = t&31 (lane-fast), chunk = t>>5 — write banks
// become ~2-way (free, m136) instead of 2-banks-x-8-way (2.9x tax).
// Evidence: R7->R8 phase-C remap halved SQ_LDS_BANK_CONFLICT 8.26M->4.68M.
// ---------------------------------------------------------------------------
__global__ __launch_bounds__(512) void attn_kernel(
    const float* __restrict__ qb, const short* __restrict__ kv,
    const int* __restrict__ topk, short* __restrict__ ctx_bf, int N)
{
  __shared__ short klds[32 * 512];     // 32 KB, XOR-4 swizzled rows
  __shared__ int sidx[NN_K];
  __shared__ float plds[8 * 32];

  int n = blockIdx.x;
  int tid = threadIdx.x;
  size_t rb = (size_t)n * E_DIM;
  if (n >= N) { ctx_bf[rb + tid] = 0; return; }

  if (tid < NN_K) sidx[tid] = topk[n * NN_K + tid];
  __syncthreads();

  int h = tid >> 6, lane = tid & 63;
  int jk = lane & 31, half = lane >> 5;
  int dbase = h * 64 + half * 32;

  // ---- preload q head-slice to regs ----
  float qv[32];
  {
    const float4* qs = (const float4*)(qb + rb + dbase);
    #pragma unroll
    for (int b = 0; b < 8; ++b) {
      float4 f = qs[b];
      qv[b*4+0] = f.x; qv[b*4+1] = f.y; qv[b*4+2] = f.z; qv[b*4+3] = f.w;
    }
  }

  // ---- stage k rows (XOR-4 swizzle), conflict-free lane->row map ----
  {
    int j = tid & 31, c = tid >> 5;    // row j, chunk c: shorts [c*32, c*32+32)
    const short8* src = (const short8*)(kv + (size_t)sidx[j] * 1024 + c * 32);
    int sw = 4 * (j & 15);
    short* row = &klds[j * 512];
    #pragma unroll
    for (int b = 0; b < 4; ++b) {
      short8 val = src[b];
      int d0 = c * 32 + b * 8;
      *(short4*)&row[(d0    ) ^ sw] = *(const short4*)&val;
      *(short4*)&row[(d0 + 4) ^ sw] = *((const short4*)&val + 1);
    }
  }
  __syncthreads();

  // ---- scores: lane (jk,half) dot over its 32 dims, b64 LDS reads ----
  float s = 0.f;
  {
    int sw = 4 * (jk & 15);
    const short* krow = &klds[jk * 512];
    #pragma unroll
    for (int i4 = 0; i4 < 8; ++i4) {
      short4 kkv = *(const short4*)&krow[(dbase + i4 * 4) ^ sw];
      s += qv[i4*4+0] * bf2f_bits(kkv.x) + qv[i4*4+1] * bf2f_bits(kkv.y)
         + qv[i4*4+2] * bf2f_bits(kkv.z) + qv[i4*4+3] * bf2f_bits(kkv.w);
    }
  }
  s += __shfl_xor(s, 32);
  s *= 0.125f;

  // ---- softmax over 32 keys ----
  float mx = s;
  #pragma unroll
  for (int o = 16; o > 0; o >>= 1) mx = fmaxf(mx, __shfl_xor(mx, o));
  float p = expf(s - mx);
  float l = p;
  #pragma unroll
  for (int o = 16; o > 0; o >>= 1) l += __shfl_xor(l, o);
  p *= (1.0f / l);
  if (half == 0) plds[h * 32 + jk] = p;
  __syncthreads();

  float pv[32];
  #pragma unroll
  for (int b = 0; b < 8; ++b) {
    float4 f = *(const float4*)&plds[h * 32 + b * 4];
    pv[b*4+0] = f.x; pv[b*4+1] = f.y; pv[b*4+2] = f.z; pv[b*4+3] = f.w;
  }

  // ---- ctx: lane = dim, coalesced bf16 v gathers ----
  int off = 512 + h * 64 + lane;
  float acc = 0.f;
  #pragma unroll
  for (int j = 0; j < NN_K; ++j)
    acc += pv[j] * bf2f_bits(kv[(size_t)sidx[j] * 1024 + off]);
  ctx_bf[rb + h * 64 + lane] = (short)f2bf(acc);
}

// ---------------------------------------------------------------------------
extern "C" void kernel_launch(void* const* d_in, const int* in_sizes, int n_in,
                              void* d_out, int out_size, void* d_ws, size_t ws_size,
                              hipStream_t stream) {
  const float* x       = (const float*)d_in[0];
  const float* coords9 = (const float*)d_in[1];
  const float* prompt  = (const float*)d_in[2];
  const float* pos_w1  = (const float*)d_in[3];
  const float* pos_b1  = (const float*)d_in[4];
  const float* ln_g    = (const float*)d_in[5];
  const float* ln_b    = (const float*)d_in[6];
  const float* wq      = (const float*)d_in[7];
  const float* wk      = (const float*)d_in[8];
  const float* wv      = (const float*)d_in[9];
  const float* bq      = (const float*)d_in[10];
  const float* bk      = (const float*)d_in[11];
  const float* bv      = (const float*)d_in[12];
  const float* wo      = (const float*)d_in[13];
  const float* bo      = (const float*)d_in[14];

  int N = in_sizes[1] / 9;                       // 2000
  int Mpad = (N + 127) & ~127;                   // 2048
  size_t PE = (size_t)Mpad * E_DIM;

  char* p = (char*)d_ws;
  short* pos_bf = (short*)p; p += PE * 2;                      // 2 MB
  short* w_bf   = (short*)p; p += (size_t)4 * 512 * 512 * 2;   // 2 MB
  float* qb     = (float*)p; p += PE * 4;                      // 4 MB
  short* kv_bf  = (short*)p; p += PE * 2 * 2;                  // 4 MB (k|v)
  short* ctx_bf = (short*)p; p += PE * 2;                      // 2 MB
  int*   topk   = (int*)p;                                     // N*32 ints

  front_kernel<<<256 + Mpad + N, 256, 0, stream>>>(
      x, coords9, prompt, pos_w1, pos_b1, ln_g, ln_b,
      wq, wk, wv, wo, w_bf, pos_bf, topk, N, Mpad);

  dim3 gq(Mpad / 64, 12);
  qkv_mfma<<<gq, 256, 0, stream>>>(pos_bf, w_bf, bq, bk, bv, qb, kv_bf, Mpad);
  attn_kernel<<<Mpad, 512, 0, stream>>>(qb, kv_bf, topk, ctx_bf, N);

  dim3 go(Mpad / 64, 4);
  out_mfma<<<go, 256, 0, stream>>>(ctx_bf, w_bf, bo, (float*)d_out, N);
}